// Round 3
// baseline (79.511 us; speedup 1.0000x reference)
//
#include <hip/hip_runtime.h>
#include <hip/hip_bf16.h>
#include <math.h>

// Problem constants (fixed by the reference)
#define BS 8
#define NQ 4096          // 64*64
#define E  256
#define NH 8
#define NP 4
#define HD 32
#define GW 64
#define GH 64
#define T  (BS * NQ)     // 32768
#define NPAD 384         // 256 value + 64 off + 32 attn + 32 pad
#define MSTR 96          // meta row: 64 offsets + 32 logits

typedef __attribute__((ext_vector_type(8))) short bf16x8;   // MFMA A/B frag
typedef __attribute__((ext_vector_type(4))) float f32x4;    // MFMA C/D frag
typedef __attribute__((ext_vector_type(8))) unsigned short u16x8;

__device__ __forceinline__ float b2f(unsigned short u) {
    union { unsigned int i; float f; } x; x.i = ((unsigned int)u) << 16; return x.f;
}
__device__ __forceinline__ unsigned short f2b(float f) {
    __hip_bfloat16 h = __float2bfloat16(f);
    return *reinterpret_cast<unsigned short*>(&h);
}
__device__ __forceinline__ void gload16(const void* g, void* l) {
    __builtin_amdgcn_global_load_lds(
        (__attribute__((address_space(1))) void*)g,
        (__attribute__((address_space(3))) void*)l, 16, 0, 0);
}

// ---------------------------------------------------------------------------
// prep: Wcat (NPAD x 256 bf16), Wo (256x256 bf16), bcat (fp32 NPAD)
// ---------------------------------------------------------------------------
__global__ __launch_bounds__(256) void prep_weights(
    const float* __restrict__ vw, const float* __restrict__ vb,
    const float* __restrict__ ow, const float* __restrict__ ob,
    const float* __restrict__ aw, const float* __restrict__ ab,
    const float* __restrict__ outw,
    unsigned short* __restrict__ Wcat, unsigned short* __restrict__ Wo,
    float* __restrict__ bcat)
{
    int i = blockIdx.x * 256 + threadIdx.x;
    if (i < NPAD * E) {
        int n = i >> 8, k = i & 255;
        float w = 0.f;
        if      (n < 256) w = vw[n * E + k];
        else if (n < 320) w = ow[(n - 256) * E + k];
        else if (n < 352) w = aw[(n - 320) * E + k];
        Wcat[i] = f2b(w);
    } else {
        int j = i - NPAD * E;
        if (j < E * E) Wo[j] = f2b(outw[j]);
    }
    if (i < NPAD) {
        float bv = 0.f;
        if      (i < 256) bv = vb[i];
        else if (i < 320) bv = ob[i - 256];
        else if (i < 352) bv = ab[i - 320];
        bcat[i] = bv;
    }
}

// ---------------------------------------------------------------------------
// GEMM1 (projection), fused fp32->bf16 on the A path.
// A = query (T x 256 fp32), W = Wcat (384 x 256 bf16).
// 128x128 tile, 4 waves (2x2), 64x64/wave, BK=32.
// A staged via regs (float4 x4 -> bf16 -> ds_write_b128 x2), B via gload_lds.
// LDS granule layout (both operands): granule g = chunk*128 + row, 16B each.
// Epilogue scatter:
//   col < 256 : Vt[((b*8 + col>>5)*4096 + q)*32 + (col&31)]   (bf16)
//   col in [256,352): Mt[t*96 + (col-256 or 64+col-320)]      (bf16)
// ---------------------------------------------------------------------------
__global__ __launch_bounds__(256) void gemm_proj(
    const float* __restrict__ Aq,
    const unsigned short* __restrict__ W,
    const float* __restrict__ bias,
    unsigned short* __restrict__ Vt,
    unsigned short* __restrict__ Mt)
{
    __shared__ __align__(16) unsigned short lds[8192];  // A: [0,4096) B: [4096,8192)

    const int tid  = threadIdx.x;
    const int lane = tid & 63;
    const int wave = tid >> 6;
    const int wm = wave >> 1, wn = wave & 1;
    const int bm = blockIdx.x * 128;
    const int bn = blockIdx.y * 128;

    const int arow  = tid >> 1;        // A staging: row 0..127
    const int ahalf = tid & 1;         // 16-float half of the 32-wide K tile
    const int lrow   = lane & 15;
    const int lchunk = lane >> 4;
    const int K = 256;

    f32x4 acc[4][4] = {};

    for (int k0 = 0; k0 < K; k0 += 32) {
        // --- A: fp32 regs -> bf16 LDS ---
        const float* ap = Aq + (size_t)(bm + arow) * K + k0 + ahalf * 16;
        float4 f0 = *(const float4*)(ap + 0);
        float4 f1 = *(const float4*)(ap + 4);
        float4 f2 = *(const float4*)(ap + 8);
        float4 f3 = *(const float4*)(ap + 12);
        // --- B: direct global->LDS ---
#pragma unroll
        for (int p = 0; p < 2; ++p) {
            int g = p * 256 + wave * 64 + lane;
            int row = g & 127, chunk = g >> 7;
            gload16(W + (size_t)(bn + row) * K + k0 + chunk * 8,
                    &lds[4096 + (size_t)g * 8]);
        }
        u16x8 g0, g1;
        g0[0]=f2b(f0.x); g0[1]=f2b(f0.y); g0[2]=f2b(f0.z); g0[3]=f2b(f0.w);
        g0[4]=f2b(f1.x); g0[5]=f2b(f1.y); g0[6]=f2b(f1.z); g0[7]=f2b(f1.w);
        g1[0]=f2b(f2.x); g1[1]=f2b(f2.y); g1[2]=f2b(f2.z); g1[3]=f2b(f2.w);
        g1[4]=f2b(f3.x); g1[5]=f2b(f3.y); g1[6]=f2b(f3.z); g1[7]=f2b(f3.w);
        *(u16x8*)&lds[(size_t)((ahalf * 2 + 0) * 128 + arow) * 8] = g0;
        *(u16x8*)&lds[(size_t)((ahalf * 2 + 1) * 128 + arow) * 8] = g1;
        __syncthreads();

        bf16x8 af[4], bfr[4];
#pragma unroll
        for (int m = 0; m < 4; ++m)
            af[m] = *(const bf16x8*)&lds[(size_t)(lchunk * 128 + wm * 64 + m * 16 + lrow) * 8];
#pragma unroll
        for (int n = 0; n < 4; ++n)
            bfr[n] = *(const bf16x8*)&lds[4096 + (size_t)(lchunk * 128 + wn * 64 + n * 16 + lrow) * 8];

#pragma unroll
        for (int m = 0; m < 4; ++m)
#pragma unroll
            for (int n = 0; n < 4; ++n)
                acc[m][n] = __builtin_amdgcn_mfma_f32_16x16x32_bf16(
                    af[m], bfr[n], acc[m][n], 0, 0, 0);
        __syncthreads();
    }

    const int orow0 = (lane >> 4) * 4;
    const int ocol  = lane & 15;
#pragma unroll
    for (int m = 0; m < 4; ++m) {
#pragma unroll
        for (int n = 0; n < 4; ++n) {
            int colg = bn + wn * 64 + n * 16 + ocol;
            if (colg >= 352) continue;
            float bv = bias[colg];
#pragma unroll
            for (int r = 0; r < 4; ++r) {
                int rowg = bm + wm * 64 + m * 16 + orow0 + r;
                unsigned short v = f2b(acc[m][n][r] + bv);
                if (colg < 256) {
                    int b = rowg >> 12, q = rowg & 4095;
                    int h = colg >> 5, ch = colg & 31;
                    Vt[((size_t)((b << 3) + h) << 12 | q) * 32 + ch] = v;
                } else if (colg < 320) {
                    Mt[(size_t)rowg * MSTR + (colg - 256)] = v;
                } else {
                    Mt[(size_t)rowg * MSTR + 64 + (colg - 320)] = v;
                }
            }
        }
    }
}

// ---------------------------------------------------------------------------
// Sampling: thread per (t, h, 8-ch group). XCD-swizzled so each XCD owns one
// batch image (Vt per b = 2 MB < 4 MB L2). Corners (x0,x1) share a 128B line.
// ---------------------------------------------------------------------------
__global__ __launch_bounds__(256) void sample_kernel(
    const unsigned short* __restrict__ Vt,
    const unsigned short* __restrict__ Mt,
    unsigned short* __restrict__ S)
{
    const int blk = ((blockIdx.x & 7) << 9) + (blockIdx.x >> 3);  // 4096 = 8*512
    const int gid = blk * 256 + threadIdx.x;
    const int d0 = gid & 3;
    const int h  = (gid >> 2) & 7;
    const int t  = gid >> 5;
    const int b  = t >> 12;
    const int q  = t & 4095;

    const float refx = (float)(q & 63) * (64.0f / 63.0f);
    const float refy = (float)(q >> 6) * (64.0f / 63.0f);

    const unsigned short* __restrict__ mrow = Mt + (size_t)t * MSTR;
    u16x8  offv = *(const u16x8*)&mrow[h * 8];
    ushort4 lg  = *(const ushort4*)&mrow[64 + h * 4];

    float l0 = b2f(lg.x), l1 = b2f(lg.y), l2 = b2f(lg.z), l3 = b2f(lg.w);
    float m = fmaxf(fmaxf(l0, l1), fmaxf(l2, l3));
    float e0 = __expf(l0 - m), e1 = __expf(l1 - m);
    float e2 = __expf(l2 - m), e3 = __expf(l3 - m);
    float inv = 1.0f / (e0 + e1 + e2 + e3);
    float at[4] = {e0 * inv, e1 * inv, e2 * inv, e3 * inv};

    const unsigned short* __restrict__ vbase =
        Vt + ((size_t)((b << 3) + h) << 12) * 32 + d0 * 8;

    float acc[8] = {};
#pragma unroll
    for (int p = 0; p < NP; ++p) {
        float ox = b2f(offv[2 * p]);
        float oy = b2f(offv[2 * p + 1]);
        float px = refx + ox - 0.5f;
        float py = refy + oy - 0.5f;
        float fx = floorf(px), fy = floorf(py);
        int x0 = (int)fx, y0 = (int)fy;
        float wx = px - fx, wy = py - fy;
        float a = at[p];

        float w00 = (1.f - wx) * (1.f - wy) * a;
        float w10 = wx * (1.f - wy) * a;
        float w01 = (1.f - wx) * wy * a;
        float w11 = wx * wy * a;

        int x1 = x0 + 1, y1 = y0 + 1;
        bool vx0 = (x0 >= 0) & (x0 < GW);
        bool vx1 = (x1 >= 0) & (x1 < GW);
        bool vy0 = (y0 >= 0) & (y0 < GH);
        bool vy1 = (y1 >= 0) & (y1 < GH);

#define CORNER(Y, X, WT)                                                      \
        {                                                                     \
            u16x8 g = *(const u16x8*)&vbase[(size_t)((Y) * GW + (X)) * 32];   \
            _Pragma("unroll")                                                 \
            for (int j = 0; j < 8; ++j) acc[j] += (WT) * b2f(g[j]);           \
        }
        if (vy0 & vx0) CORNER(y0, x0, w00);
        if (vy0 & vx1) CORNER(y0, x1, w10);
        if (vy1 & vx0) CORNER(y1, x0, w01);
        if (vy1 & vx1) CORNER(y1, x1, w11);
#undef CORNER
    }

    u16x8 o;
#pragma unroll
    for (int j = 0; j < 8; ++j) o[j] = f2b(acc[j]);
    *(u16x8*)&S[(size_t)t * E + h * HD + d0 * 8] = o;
}

// ---------------------------------------------------------------------------
// GEMM2 (output projection): S (T x 256 bf16) @ Wo^T + out_b + 2*query.
// Both operands via gload_lds. fp32 output.
// ---------------------------------------------------------------------------
__global__ __launch_bounds__(256) void gemm_out(
    const unsigned short* __restrict__ A,
    const unsigned short* __restrict__ W,
    const float* __restrict__ bias,
    const float* __restrict__ resid,
    float* __restrict__ Out)
{
    __shared__ __align__(16) unsigned short lds[8192];

    const int tid  = threadIdx.x;
    const int lane = tid & 63;
    const int wave = tid >> 6;
    const int wm = wave >> 1, wn = wave & 1;
    const int bm = blockIdx.x * 128;
    const int bn = blockIdx.y * 128;
    const int lrow   = lane & 15;
    const int lchunk = lane >> 4;
    const int K = 256, N = 256;

    f32x4 acc[4][4] = {};

    for (int k0 = 0; k0 < K; k0 += 32) {
#pragma unroll
        for (int p = 0; p < 2; ++p) {
            int g = p * 256 + wave * 64 + lane;
            int row = g & 127, chunk = g >> 7;
            gload16(A + (size_t)(bm + row) * K + k0 + chunk * 8,
                    &lds[(size_t)g * 8]);
            gload16(W + (size_t)(bn + row) * K + k0 + chunk * 8,
                    &lds[4096 + (size_t)g * 8]);
        }
        __syncthreads();

        bf16x8 af[4], bfr[4];
#pragma unroll
        for (int m = 0; m < 4; ++m)
            af[m] = *(const bf16x8*)&lds[(size_t)(lchunk * 128 + wm * 64 + m * 16 + lrow) * 8];
#pragma unroll
        for (int n = 0; n < 4; ++n)
            bfr[n] = *(const bf16x8*)&lds[4096 + (size_t)(lchunk * 128 + wn * 64 + n * 16 + lrow) * 8];

#pragma unroll
        for (int m = 0; m < 4; ++m)
#pragma unroll
            for (int n = 0; n < 4; ++n)
                acc[m][n] = __builtin_amdgcn_mfma_f32_16x16x32_bf16(
                    af[m], bfr[n], acc[m][n], 0, 0, 0);
        __syncthreads();
    }

    const int orow0 = (lane >> 4) * 4;
    const int ocol  = lane & 15;
#pragma unroll
    for (int m = 0; m < 4; ++m) {
#pragma unroll
        for (int n = 0; n < 4; ++n) {
            int colg = bn + wn * 64 + n * 16 + ocol;
            float bv = bias[colg];
#pragma unroll
            for (int r = 0; r < 4; ++r) {
                int rowg = bm + wm * 64 + m * 16 + orow0 + r;
                Out[(size_t)rowg * N + colg] =
                    acc[m][n][r] + bv + 2.0f * resid[(size_t)rowg * N + colg];
            }
        }
    }
}

// ---------------------------------------------------------------------------
extern "C" void kernel_launch(void* const* d_in, const int* in_sizes, int n_in,
                              void* d_out, int out_size, void* d_ws, size_t ws_size,
                              hipStream_t stream)
{
    const float* query   = (const float*)d_in[0];
    const float* value_w = (const float*)d_in[1];
    const float* value_b = (const float*)d_in[2];
    const float* off_w   = (const float*)d_in[3];
    const float* off_b   = (const float*)d_in[4];
    const float* attn_w  = (const float*)d_in[5];
    const float* attn_b  = (const float*)d_in[6];
    const float* out_w   = (const float*)d_in[7];
    const float* out_b   = (const float*)d_in[8];

    char* w = (char*)d_ws;
    unsigned short* Vt   = (unsigned short*)w;  w += (size_t)T * E * 2;      // 16 MB
    unsigned short* Mt   = (unsigned short*)w;  w += (size_t)T * MSTR * 2;   // 6 MB
    unsigned short* S    = (unsigned short*)w;  w += (size_t)T * E * 2;      // 16 MB
    unsigned short* Wcat = (unsigned short*)w;  w += (size_t)NPAD * E * 2;
    unsigned short* Wo   = (unsigned short*)w;  w += (size_t)E * E * 2;
    float*          bcat = (float*)w;

    prep_weights<<<(NPAD * E + E * E + 255) / 256, 256, 0, stream>>>(
        value_w, value_b, off_w, off_b, attn_w, attn_b, out_w, Wcat, Wo, bcat);

    dim3 g1(T / 128, NPAD / 128);
    gemm_proj<<<g1, 256, 0, stream>>>(query, Wcat, bcat, Vt, Mt);

    sample_kernel<<<T * 32 / 256, 256, 0, stream>>>(Vt, Mt, S);

    dim3 g2(T / 128, E / 128);
    gemm_out<<<g2, 256, 0, stream>>>(S, Wo, out_b, query, (float*)d_out);
}